// Round 4
// baseline (364.397 us; speedup 1.0000x reference)
//
#include <hip/hip_runtime.h>
#include <math.h>

#define S_LEN 1024
#define NHEAD 16
#define HDIM 64
#define LHDIM 16

typedef __bf16 bf16;
typedef bf16 bf16x4 __attribute__((ext_vector_type(4)));
typedef bf16 bf16x8 __attribute__((ext_vector_type(8)));
typedef float f32x4 __attribute__((ext_vector_type(4)));

#define MFMA16(a, b, c) __builtin_amdgcn_mfma_f32_16x16x32_bf16(a, b, c, 0, 0, 0)

// async global->LDS, 16B per lane; lds ptr must be wave-uniform
__device__ __forceinline__ void gl2lds16(const void* g, void* l)
{
    __builtin_amdgcn_global_load_lds(
        (const __attribute__((address_space(1))) unsigned int*)g,
        (__attribute__((address_space(3))) unsigned int*)l,
        16, 0, 0);
}

// ---------------------------------------------------------------------------
// flat fp32 -> bf16 convert (x4 per thread)
// ---------------------------------------------------------------------------
__global__ __launch_bounds__(256)
void cvt4_kernel(const float* __restrict__ in, bf16* __restrict__ out, int n4)
{
    int i = blockIdx.x * 256 + threadIdx.x;
    if (i < n4) {
        float4 v = *(const float4*)&in[(size_t)i * 4];
        bf16x4 o = { (bf16)v.x, (bf16)v.y, (bf16)v.z, (bf16)v.w };
        *(bf16x4*)&out[(size_t)i * 4] = o;
    }
}

// ---------------------------------------------------------------------------
// W [K][N] fp32 -> Wt [N][K] bf16 (LDS-tiled 64x64 transpose)
// ---------------------------------------------------------------------------
__global__ __launch_bounds__(256)
void cvtT_kernel(const float* __restrict__ W0, const float* __restrict__ W1,
                 const float* __restrict__ W2,
                 bf16* __restrict__ T0, bf16* __restrict__ T1, bf16* __restrict__ T2,
                 int K, int N)
{
    const float* W; bf16* T;
    if (blockIdx.z == 0)      { W = W0; T = T0; }
    else if (blockIdx.z == 1) { W = W1; T = T1; }
    else                      { W = W2; T = T2; }

    __shared__ float Ts[64][65];
    const int t  = threadIdx.x;
    const int k0 = blockIdx.y << 6;
    const int n0 = blockIdx.x << 6;

    #pragma unroll
    for (int p = 0; p < 4; p++) {
        int li = p * 256 + t;
        int r  = li >> 4, c4 = (li & 15) << 2;
        float4 v = *(const float4*)&W[(size_t)(k0 + r) * N + n0 + c4];
        Ts[r][c4 + 0] = v.x; Ts[r][c4 + 1] = v.y;
        Ts[r][c4 + 2] = v.z; Ts[r][c4 + 3] = v.w;
    }
    __syncthreads();

    int r2 = t >> 2, ks = (t & 3) << 4;
    bf16x8 o0, o1;
    #pragma unroll
    for (int u = 0; u < 8; u++) o0[u] = (bf16)Ts[ks + u][r2];
    #pragma unroll
    for (int u = 0; u < 8; u++) o1[u] = (bf16)Ts[ks + 8 + u][r2];
    *(bf16x8*)&T[(size_t)(n0 + r2) * K + k0 + ks]     = o0;
    *(bf16x8*)&T[(size_t)(n0 + r2) * K + k0 + ks + 8] = o1;
}

// ---------------------------------------------------------------------------
// MFMA projection GEMM (m97 pattern): O = (X @ Wt^T + b) * scale, bf16 out,
// head-split. 128x128 tile, BK=32, global_load_lds x16.
// ---------------------------------------------------------------------------
template<int KDIM, int NHD_>
__global__ __launch_bounds__(256, 2)
void projm_kernel(const bf16* __restrict__ X,
                  const bf16* __restrict__ Wt0, const float* __restrict__ B0,
                  const bf16* __restrict__ Wt1, const float* __restrict__ B1,
                  const bf16* __restrict__ Wt2, const float* __restrict__ B2,
                  bf16* __restrict__ O0, bf16* __restrict__ O1, bf16* __restrict__ O2,
                  float s0)
{
    const bf16* Wt; const float* Bi; bf16* O; float scale;
    if (blockIdx.z == 0)      { Wt = Wt0; Bi = B0; O = O0; scale = s0; }
    else if (blockIdx.z == 1) { Wt = Wt1; Bi = B1; O = O1; scale = 1.0f; }
    else                      { Wt = Wt2; Bi = B2; O = O2; scale = 1.0f; }

    __shared__ bf16 As[128 * 32];
    __shared__ bf16 Bs[128 * 32];

    const int t    = threadIdx.x;
    const int wv   = t >> 6;
    const int l64  = t & 63;
    const int ln   = l64 & 15;
    const int quad = l64 >> 4;
    const int wm   = wv & 1;
    const int wn   = wv >> 1;
    const int m0   = blockIdx.y << 7;
    const int n0   = blockIdx.x << 7;

    const int arow = l64 >> 2;
    const int koff = (l64 & 3) << 3;

    f32x4 acc[4][4];
    #pragma unroll
    for (int i = 0; i < 4; i++)
        #pragma unroll
        for (int j = 0; j < 4; j++) acc[i][j] = (f32x4)0.0f;

    for (int k0 = 0; k0 < KDIM; k0 += 32) {
        #pragma unroll
        for (int c = 0; c < 2; c++) {
            int g = (c * 4 + wv) << 4;
            gl2lds16(&X [(size_t)(m0 + g + arow) * KDIM + k0 + koff], &As[(c * 4 + wv) * 512]);
            gl2lds16(&Wt[(size_t)(n0 + g + arow) * KDIM + k0 + koff], &Bs[(c * 4 + wv) * 512]);
        }
        __syncthreads();

        bf16x8 af[4], bfv[4];
        #pragma unroll
        for (int mt = 0; mt < 4; mt++)
            af[mt] = *(const bf16x8*)&As[(wm * 64 + mt * 16 + ln) * 32 + quad * 8];
        #pragma unroll
        for (int nt = 0; nt < 4; nt++)
            bfv[nt] = *(const bf16x8*)&Bs[(wn * 64 + nt * 16 + ln) * 32 + quad * 8];
        #pragma unroll
        for (int mt = 0; mt < 4; mt++)
            #pragma unroll
            for (int nt = 0; nt < 4; nt++)
                acc[mt][nt] = MFMA16(af[mt], bfv[nt], acc[mt][nt]);
        __syncthreads();
    }

    #pragma unroll
    for (int nt = 0; nt < 4; nt++) {
        int n  = n0 + wn * 64 + nt * 16 + ln;
        float bia = Bi[n];
        int hh = n / NHD_;
        int dd = n % NHD_;
        #pragma unroll
        for (int mt = 0; mt < 4; mt++) {
            #pragma unroll
            for (int reg = 0; reg < 4; reg++) {
                int m  = m0 + wm * 64 + mt * 16 + quad * 4 + reg;
                int bb = m >> 10;
                int s  = m & 1023;
                O[((size_t)((bb * NHEAD + hh) << 10) + s) * NHD_ + dd] =
                    (bf16)((acc[mt][nt][reg] + bia) * scale);
            }
        }
    }
}

// ---------------------------------------------------------------------------
// Fused dual-stream MFMA attention with relative-position bias.
// Q'/K'/E operands loaded directly from global as MFMA fragments (no LDS).
// LDS only for: V^T / LV^T (transpose), Hs (skew gather), Ps (layout xform).
// Hs/Ps are same-wave produce/consume -> no barrier needed for them.
// 2 barriers per K-iteration (guard cooperative V staging only).
// ---------------------------------------------------------------------------
__global__ __launch_bounds__(256, 4)
void attn_kernel(const bf16* __restrict__ qg, const bf16* __restrict__ kg,
                 const bf16* __restrict__ vg, const bf16* __restrict__ lqg,
                 const bf16* __restrict__ lkg, const bf16* __restrict__ lvg,
                 const float* __restrict__ maskg, const bf16* __restrict__ demb,
                 float* __restrict__ octx, float* __restrict__ olctx)
{
    __shared__ bf16 VsT[64][72];    // [d][r]
    __shared__ bf16 LVsT[16][72];   // [d][r]
    __shared__ bf16 Ps[64][72];     // [m][r]
    __shared__ bf16 Hs[64][132];    // [m][c]

    const int t    = threadIdx.x;
    const int w    = t >> 6;
    const int lane = t & 63;
    const int ln   = lane & 15;
    const int quad = lane >> 4;
    const int m0   = w << 4;

    const int bh = blockIdx.y;
    const int b  = bh >> 4;
    const int h  = bh & 15;
    const int l0 = blockIdx.x << 6;

    const bf16* qb  = qg  + (size_t)bh * (S_LEN * HDIM);
    const bf16* kb  = kg  + (size_t)bh * (S_LEN * HDIM);
    const bf16* vb  = vg  + (size_t)bh * (S_LEN * HDIM);
    const bf16* lqb = lqg + (size_t)bh * (S_LEN * LHDIM);
    const bf16* lkb = lkg + (size_t)bh * (S_LEN * LHDIM);
    const bf16* lvb = lvg + (size_t)bh * (S_LEN * LHDIM);

    bf16x8 zer;
    #pragma unroll
    for (int u = 0; u < 8; u++) zer[u] = (bf16)0.0f;

    // ---- Q' A-fragments direct from global (row = l0+m0+ln) ----
    bf16x8 af[3];
    {
        const int qrow = l0 + m0 + ln;
        af[0] = *(const bf16x8*)&qb[(size_t)qrow * HDIM + quad * 8];
        af[1] = *(const bf16x8*)&qb[(size_t)qrow * HDIM + 32 + quad * 8];
        af[2] = (quad < 2) ? *(const bf16x8*)&lqb[(size_t)qrow * LHDIM + quad * 8] : zer;
    }

    float mrow[4], lrow[4];
    f32x4 co[4];
    f32x4 cl;
    #pragma unroll
    for (int i = 0; i < 4; i++) { mrow[i] = -1e30f; lrow[i] = 0.0f; co[i] = (f32x4)0.0f; }
    cl = (f32x4)0.0f;

    for (int r0 = 0; r0 < S_LEN; r0 += 64) {
        __syncthreads();   // previous PV reads of VsT/LVsT complete

        // ---- stage V^T, LV^T (conflict-free column-major stores) ----
        #pragma unroll
        for (int r = 0; r < 2; r++) {
            int li = r * 256 + t;
            int rr = li & 63, d8 = (li >> 6) << 3;
            bf16x8 x = *(const bf16x8*)&vb[(size_t)(r0 + rr) * HDIM + d8];
            #pragma unroll
            for (int u = 0; u < 8; u++) VsT[d8 + u][rr] = x[u];
        }
        if (t < 128) {
            int rr = t & 63, d8 = (t >> 6) << 3;
            bf16x8 x = *(const bf16x8*)&lvb[(size_t)(r0 + rr) * LHDIM + d8];
            #pragma unroll
            for (int u = 0; u < 8; u++) LVsT[d8 + u][rr] = x[u];
        }

        // ---- H = Q'[:, :64] @ E^T, E fragments direct from global ----
        const int jb = l0 - r0 + 1984;
        f32x4 hh[8];
        #pragma unroll
        for (int ct = 0; ct < 8; ct++) {
            hh[ct] = (f32x4)0.0f;
            #pragma unroll
            for (int ks = 0; ks < 2; ks++)
                hh[ct] = MFMA16(af[ks],
                    *(const bf16x8*)&demb[(size_t)(jb + ct * 16 + ln) * HDIM + ks * 32 + quad * 8],
                    hh[ct]);
        }
        // write Hs (own wave stripe only)
        #pragma unroll
        for (int ct = 0; ct < 8; ct++)
            #pragma unroll
            for (int reg = 0; reg < 4; reg++)
                Hs[m0 + quad * 4 + reg][ct * 16 + ln] = (bf16)hh[ct][reg];

        // ---- scores = Q' @ K'^T, K' fragments direct from global ----
        f32x4 sc[4];
        #pragma unroll
        for (int nt = 0; nt < 4; nt++) {
            const int krow = r0 + nt * 16 + ln;
            sc[nt] = (f32x4)0.0f;
            sc[nt] = MFMA16(af[0], *(const bf16x8*)&kb[(size_t)krow * HDIM + quad * 8], sc[nt]);
            sc[nt] = MFMA16(af[1], *(const bf16x8*)&kb[(size_t)krow * HDIM + 32 + quad * 8], sc[nt]);
            bf16x8 k2 = (quad < 2) ? *(const bf16x8*)&lkb[(size_t)krow * LHDIM + quad * 8] : zer;
            sc[nt] = MFMA16(af[2], k2, sc[nt]);
        }

        // ---- softmax (rows quad*4+reg of wave stripe; Hs read same-wave) ----
        float msv[4];
        #pragma unroll
        for (int nt = 0; nt < 4; nt++) msv[nt] = maskg[b * S_LEN + r0 + nt * 16 + ln];

        float sv[4][4];
        #pragma unroll
        for (int nt = 0; nt < 4; nt++) {
            int n = nt * 16 + ln;
            #pragma unroll
            for (int reg = 0; reg < 4; reg++) {
                int mf = m0 + quad * 4 + reg;
                sv[nt][reg] = sc[nt][reg] + (float)Hs[mf][mf - n + 63] + msv[nt];
            }
        }
        #pragma unroll
        for (int reg = 0; reg < 4; reg++) {
            float rmax = fmaxf(fmaxf(sv[0][reg], sv[1][reg]), fmaxf(sv[2][reg], sv[3][reg]));
            #pragma unroll
            for (int off = 1; off < 16; off <<= 1)
                rmax = fmaxf(rmax, __shfl_xor(rmax, off));
            float mnew  = fmaxf(mrow[reg], rmax);
            float alpha = __expf(mrow[reg] - mnew);
            float rsum = 0.0f;
            #pragma unroll
            for (int nt = 0; nt < 4; nt++) {
                float p = __expf(sv[nt][reg] - mnew);
                sv[nt][reg] = p;
                rsum += p;
            }
            #pragma unroll
            for (int off = 1; off < 16; off <<= 1)
                rsum += __shfl_xor(rsum, off);
            lrow[reg] = lrow[reg] * alpha + rsum;
            mrow[reg] = mnew;
            #pragma unroll
            for (int nt = 0; nt < 4; nt++) co[nt][reg] *= alpha;
            cl[reg] *= alpha;
        }
        // write P (own wave stripe)
        #pragma unroll
        for (int nt = 0; nt < 4; nt++)
            #pragma unroll
            for (int reg = 0; reg < 4; reg++)
                Ps[m0 + quad * 4 + reg][nt * 16 + ln] = (bf16)sv[nt][reg];

        __syncthreads();   // VsT/LVsT staging visible to all waves

        // ---- ctx += P @ V ; lctx += P @ LV (Ps read same-wave) ----
        #pragma unroll
        for (int ks = 0; ks < 2; ks++) {
            bf16x8 ap = *(const bf16x8*)&Ps[m0 + ln][ks * 32 + quad * 8];
            cl = MFMA16(ap, *(const bf16x8*)&LVsT[ln][ks * 32 + quad * 8], cl);
            #pragma unroll
            for (int nt = 0; nt < 4; nt++)
                co[nt] = MFMA16(ap,
                                *(const bf16x8*)&VsT[nt * 16 + ln][ks * 32 + quad * 8],
                                co[nt]);
        }
    }

    // ---- epilogue ----
    #pragma unroll
    for (int reg = 0; reg < 4; reg++) {
        int s = l0 + m0 + quad * 4 + reg;
        float inv = 1.0f / lrow[reg];
        #pragma unroll
        for (int nt = 0; nt < 4; nt++)
            octx[(size_t)(b * S_LEN + s) * 1024 + h * 64 + nt * 16 + ln] = co[nt][reg] * inv;
        olctx[(size_t)(b * S_LEN + s) * 256 + h * 16 + ln] = cl[reg] * inv;
    }
}

// ---------------------------------------------------------------------------
extern "C" void kernel_launch(void* const* d_in, const int* in_sizes, int n_in,
                              void* d_out, int out_size, void* d_ws, size_t ws_size,
                              hipStream_t stream)
{
    (void)in_sizes; (void)n_in; (void)out_size; (void)ws_size;

    const float* hs   = (const float*)d_in[0];
    const float* lin  = (const float*)d_in[1];
    const float* mask = (const float*)d_in[2];
    const float* wq  = (const float*)d_in[3];  const float* bq  = (const float*)d_in[4];
    const float* wk  = (const float*)d_in[5];  const float* bk  = (const float*)d_in[6];
    const float* wv  = (const float*)d_in[7];  const float* bv  = (const float*)d_in[8];
    const float* lwq = (const float*)d_in[9];  const float* lbq = (const float*)d_in[10];
    const float* lwk = (const float*)d_in[11]; const float* lbk = (const float*)d_in[12];
    const float* lwv = (const float*)d_in[13]; const float* lbv = (const float*)d_in[14];
    const float* demb = (const float*)d_in[15];

    bf16* ws = (bf16*)d_ws;
    bf16* q    = ws;                  // 4,194,304
    bf16* k    = ws + 4194304;
    bf16* v    = ws + 8388608;
    bf16* lq   = ws + 12582912;       // 1,048,576
    bf16* lk   = ws + 13631488;
    bf16* lv   = ws + 14680064;
    bf16* de   = ws + 15728640;       // 262,080
    bf16* hsb  = ws + 16000000;       // 4,194,304
    bf16* linb = ws + 20194304;       // 1,048,576
    bf16* wqt  = ws + 21242880;       // 1,048,576
    bf16* wkt  = ws + 22291456;
    bf16* wvt  = ws + 23340032;
    bf16* lwqt = ws + 24388608;       // 65,536
    bf16* lwkt = ws + 24454144;
    bf16* lwvt = ws + 24519680;

    cvt4_kernel<<<dim3(4096), 256, 0, stream>>>(hs,  hsb,  1048576);
    cvt4_kernel<<<dim3(1024), 256, 0, stream>>>(lin, linb, 262144);
    cvt4_kernel<<<dim3(256),  256, 0, stream>>>(demb, de,  65520);
    cvtT_kernel<<<dim3(16, 16, 3), 256, 0, stream>>>(wq, wk, wv, wqt, wkt, wvt, 1024, 1024);
    cvtT_kernel<<<dim3(4, 4, 3),   256, 0, stream>>>(lwq, lwk, lwv, lwqt, lwkt, lwvt, 256, 256);

    projm_kernel<1024, 64><<<dim3(8, 32, 3), 256, 0, stream>>>(
        hsb, wqt, bq, wkt, bk, wvt, bv, q, k, v, 0.125f);
    projm_kernel<256, 16><<<dim3(2, 32, 3), 256, 0, stream>>>(
        linb, lwqt, lbq, lwkt, lbk, lwvt, lbv, lq, lk, lv, 0.25f);

    float* octx  = (float*)d_out;
    float* olctx = (float*)d_out + 4194304;
    attn_kernel<<<dim3(16, 64), 256, 0, stream>>>(
        q, k, v, lq, lk, lv, mask, de, octx, olctx);
}

// Round 6
// 292.385 us; speedup vs baseline: 1.2463x; 1.2463x over previous
//
#include <hip/hip_runtime.h>
#include <math.h>

#define S_LEN 1024
#define NHEAD 16
#define HDIM 64
#define LHDIM 16

typedef __bf16 bf16;
typedef bf16 bf16x4 __attribute__((ext_vector_type(4)));
typedef bf16 bf16x8 __attribute__((ext_vector_type(8)));
typedef float f32x4 __attribute__((ext_vector_type(4)));

#define MFMA16(a, b, c) __builtin_amdgcn_mfma_f32_16x16x32_bf16(a, b, c, 0, 0, 0)

// async global->LDS, 16B per lane; lds ptr must be wave-uniform
__device__ __forceinline__ void gl2lds16(const void* g, void* l)
{
    __builtin_amdgcn_global_load_lds(
        (const __attribute__((address_space(1))) unsigned int*)g,
        (__attribute__((address_space(3))) unsigned int*)l,
        16, 0, 0);
}

// ---------------------------------------------------------------------------
// flat fp32 -> bf16 convert (x4 per thread)
// ---------------------------------------------------------------------------
__global__ __launch_bounds__(256)
void cvt4_kernel(const float* __restrict__ in, bf16* __restrict__ out, int n4)
{
    int i = blockIdx.x * 256 + threadIdx.x;
    if (i < n4) {
        float4 v = *(const float4*)&in[(size_t)i * 4];
        bf16x4 o = { (bf16)v.x, (bf16)v.y, (bf16)v.z, (bf16)v.w };
        *(bf16x4*)&out[(size_t)i * 4] = o;
    }
}

// ---------------------------------------------------------------------------
// W [K][N] fp32 -> Wt [N][K] bf16 (LDS-tiled 64x64 transpose)
// ---------------------------------------------------------------------------
__global__ __launch_bounds__(256)
void cvtT_kernel(const float* __restrict__ W0, const float* __restrict__ W1,
                 const float* __restrict__ W2,
                 bf16* __restrict__ T0, bf16* __restrict__ T1, bf16* __restrict__ T2,
                 int K, int N)
{
    const float* W; bf16* T;
    if (blockIdx.z == 0)      { W = W0; T = T0; }
    else if (blockIdx.z == 1) { W = W1; T = T1; }
    else                      { W = W2; T = T2; }

    __shared__ float Ts[64][65];
    const int t  = threadIdx.x;
    const int k0 = blockIdx.y << 6;
    const int n0 = blockIdx.x << 6;

    #pragma unroll
    for (int p = 0; p < 4; p++) {
        int li = p * 256 + t;
        int r  = li >> 4, c4 = (li & 15) << 2;
        float4 v = *(const float4*)&W[(size_t)(k0 + r) * N + n0 + c4];
        Ts[r][c4 + 0] = v.x; Ts[r][c4 + 1] = v.y;
        Ts[r][c4 + 2] = v.z; Ts[r][c4 + 3] = v.w;
    }
    __syncthreads();

    int r2 = t >> 2, ks = (t & 3) << 4;
    bf16x8 o0, o1;
    #pragma unroll
    for (int u = 0; u < 8; u++) o0[u] = (bf16)Ts[ks + u][r2];
    #pragma unroll
    for (int u = 0; u < 8; u++) o1[u] = (bf16)Ts[ks + 8 + u][r2];
    *(bf16x8*)&T[(size_t)(n0 + r2) * K + k0 + ks]     = o0;
    *(bf16x8*)&T[(size_t)(n0 + r2) * K + k0 + ks + 8] = o1;
}

// ---------------------------------------------------------------------------
// MFMA projection GEMM (m97 pattern): O = (X @ Wt^T + b) * scale, bf16 out,
// head-split. 128x128 tile, BK=32, global_load_lds x16.
// ---------------------------------------------------------------------------
template<int KDIM, int NHD_>
__global__ __launch_bounds__(256, 2)
void projm_kernel(const bf16* __restrict__ X,
                  const bf16* __restrict__ Wt0, const float* __restrict__ B0,
                  const bf16* __restrict__ Wt1, const float* __restrict__ B1,
                  const bf16* __restrict__ Wt2, const float* __restrict__ B2,
                  bf16* __restrict__ O0, bf16* __restrict__ O1, bf16* __restrict__ O2,
                  float s0)
{
    const bf16* Wt; const float* Bi; bf16* O; float scale;
    if (blockIdx.z == 0)      { Wt = Wt0; Bi = B0; O = O0; scale = s0; }
    else if (blockIdx.z == 1) { Wt = Wt1; Bi = B1; O = O1; scale = 1.0f; }
    else                      { Wt = Wt2; Bi = B2; O = O2; scale = 1.0f; }

    __shared__ bf16 As[128 * 32];
    __shared__ bf16 Bs[128 * 32];

    const int t    = threadIdx.x;
    const int wv   = t >> 6;
    const int l64  = t & 63;
    const int ln   = l64 & 15;
    const int quad = l64 >> 4;
    const int wm   = wv & 1;
    const int wn   = wv >> 1;
    const int m0   = blockIdx.y << 7;
    const int n0   = blockIdx.x << 7;

    const int arow = l64 >> 2;
    const int koff = (l64 & 3) << 3;

    f32x4 acc[4][4];
    #pragma unroll
    for (int i = 0; i < 4; i++)
        #pragma unroll
        for (int j = 0; j < 4; j++) acc[i][j] = (f32x4)0.0f;

    for (int k0 = 0; k0 < KDIM; k0 += 32) {
        #pragma unroll
        for (int c = 0; c < 2; c++) {
            int g = (c * 4 + wv) << 4;
            gl2lds16(&X [(size_t)(m0 + g + arow) * KDIM + k0 + koff], &As[(c * 4 + wv) * 512]);
            gl2lds16(&Wt[(size_t)(n0 + g + arow) * KDIM + k0 + koff], &Bs[(c * 4 + wv) * 512]);
        }
        __syncthreads();

        bf16x8 af[4], bfv[4];
        #pragma unroll
        for (int mt = 0; mt < 4; mt++)
            af[mt] = *(const bf16x8*)&As[(wm * 64 + mt * 16 + ln) * 32 + quad * 8];
        #pragma unroll
        for (int nt = 0; nt < 4; nt++)
            bfv[nt] = *(const bf16x8*)&Bs[(wn * 64 + nt * 16 + ln) * 32 + quad * 8];
        #pragma unroll
        for (int mt = 0; mt < 4; mt++)
            #pragma unroll
            for (int nt = 0; nt < 4; nt++)
                acc[mt][nt] = MFMA16(af[mt], bfv[nt], acc[mt][nt]);
        __syncthreads();
    }

    #pragma unroll
    for (int nt = 0; nt < 4; nt++) {
        int n  = n0 + wn * 64 + nt * 16 + ln;
        float bia = Bi[n];
        int hh = n / NHD_;
        int dd = n % NHD_;
        #pragma unroll
        for (int mt = 0; mt < 4; mt++) {
            #pragma unroll
            for (int reg = 0; reg < 4; reg++) {
                int m  = m0 + wm * 64 + mt * 16 + quad * 4 + reg;
                int bb = m >> 10;
                int s  = m & 1023;
                O[((size_t)((bb * NHEAD + hh) << 10) + s) * NHD_ + dd] =
                    (bf16)((acc[mt][nt][reg] + bia) * scale);
            }
        }
    }
}

// ---------------------------------------------------------------------------
// Fused dual-stream MFMA attention with relative-position bias.
// - K' (text|lk|0pad) staged in LDS (coalesced): score MFMAs LDS-fed.
//   (R5 bug fixed: BOTH 32-col halves of the text-K tile are now staged.)
// - E fragments register-prefetched at iteration top (direct global),
//   consumed after staging + 2 barriers. Each wave computes only its
//   needed 5 H col-tiles (cols [m0, m0+80)).
// - Q' fragments in registers (loaded once).
// - Hs/Ps are same-wave produce/consume (no barrier); 2 barriers/iter total.
// LDS = 44.8 KiB -> 3 blocks/CU.
// ---------------------------------------------------------------------------
__global__ __launch_bounds__(256, 3)
void attn_kernel(const bf16* __restrict__ qg, const bf16* __restrict__ kg,
                 const bf16* __restrict__ vg, const bf16* __restrict__ lqg,
                 const bf16* __restrict__ lkg, const bf16* __restrict__ lvg,
                 const float* __restrict__ maskg, const bf16* __restrict__ demb,
                 float* __restrict__ octx, float* __restrict__ olctx)
{
    __shared__ bf16 Ks[64][104];    // [r][f]: text [0,64) | lk [64,80) | 0 [80,96) | pad
    __shared__ bf16 VsT[64][72];    // [d][r]
    __shared__ bf16 LVsT[16][72];   // [d][r]
    __shared__ bf16 Ps[64][72];     // [m][r]
    __shared__ bf16 Hs[64][84];     // [m][c - m0], c in [m0, m0+80)

    const int t    = threadIdx.x;
    const int w    = t >> 6;
    const int lane = t & 63;
    const int ln   = lane & 15;
    const int quad = lane >> 4;
    const int m0   = w << 4;

    const int bh = blockIdx.y;
    const int b  = bh >> 4;
    const int h  = bh & 15;
    const int l0 = blockIdx.x << 6;

    const bf16* qb  = qg  + (size_t)bh * (S_LEN * HDIM);
    const bf16* kb  = kg  + (size_t)bh * (S_LEN * HDIM);
    const bf16* vb  = vg  + (size_t)bh * (S_LEN * HDIM);
    const bf16* lqb = lqg + (size_t)bh * (S_LEN * LHDIM);
    const bf16* lkb = lkg + (size_t)bh * (S_LEN * LHDIM);
    const bf16* lvb = lvg + (size_t)bh * (S_LEN * LHDIM);

    bf16x8 zer;
    #pragma unroll
    for (int u = 0; u < 8; u++) zer[u] = (bf16)0.0f;

    // zero-fill Ks pad cols [80,96) once (never overwritten in-loop)
    if (t < 128) {
        int row = t >> 1, h8 = (t & 1) << 3;
        *(bf16x8*)&Ks[row][80 + h8] = zer;
    }

    // ---- Q' A-fragments direct from global (row = l0+m0+ln) ----
    bf16x8 af[3];
    {
        const int qrow = l0 + m0 + ln;
        af[0] = *(const bf16x8*)&qb[(size_t)qrow * HDIM + quad * 8];
        af[1] = *(const bf16x8*)&qb[(size_t)qrow * HDIM + 32 + quad * 8];
        af[2] = (quad < 2) ? *(const bf16x8*)&lqb[(size_t)qrow * LHDIM + quad * 8] : zer;
    }

    // staging index precompute
    const int krow = t >> 2, kc8 = (t & 3) << 3;        // K text: cols {0..24} and {32..56}
    const int lkrow = t >> 1, lh8 = (t & 1) << 3;       // lk (t<128)
    const int vr0 = t & 63,        vd80 = (t >> 6) << 3;         // V d8 in {0..24}
    const int vr1 = t & 63,        vd81 = 32 + ((t >> 6) << 3);  // V d8 in {32..56}
    const int lvr = t & 63,        lvd8 = (t >> 6) << 3;         // LV (t<128)

    float mrow[4], lrow[4];
    f32x4 co[4];
    f32x4 cl;
    #pragma unroll
    for (int i = 0; i < 4; i++) { mrow[i] = -1e30f; lrow[i] = 0.0f; co[i] = (f32x4)0.0f; }
    cl = (f32x4)0.0f;

    for (int r0 = 0; r0 < S_LEN; r0 += 64) {
        const int jb = l0 - r0 + 1984;

        // ---- register prefetch: E fragments, mask, staging data ----
        bf16x8 ef[5][2];
        #pragma unroll
        for (int ct = 0; ct < 5; ct++) {
            const bf16* ep = &demb[(size_t)(jb + m0 + ct * 16 + ln) * HDIM + quad * 8];
            ef[ct][0] = *(const bf16x8*)ep;
            ef[ct][1] = *(const bf16x8*)(ep + 32);
        }
        float msv[4];
        #pragma unroll
        for (int nt = 0; nt < 4; nt++) msv[nt] = maskg[b * S_LEN + r0 + nt * 16 + ln];

        bf16x8 kx0 = *(const bf16x8*)&kb[(size_t)(r0 + krow) * HDIM + kc8];
        bf16x8 kx1 = *(const bf16x8*)&kb[(size_t)(r0 + krow) * HDIM + 32 + kc8];
        bf16x8 lkx = (t < 128) ? *(const bf16x8*)&lkb[(size_t)(r0 + lkrow) * LHDIM + lh8] : zer;
        bf16x8 vx0 = *(const bf16x8*)&vb[(size_t)(r0 + vr0) * HDIM + vd80];
        bf16x8 vx1 = *(const bf16x8*)&vb[(size_t)(r0 + vr1) * HDIM + vd81];
        bf16x8 lvx = (t < 128) ? *(const bf16x8*)&lvb[(size_t)(r0 + lvr) * LHDIM + lvd8] : zer;

        __syncthreads();   // B1: previous-iteration LDS reads complete

        // ---- stage K', V^T, LV^T ----
        *(bf16x8*)&Ks[krow][kc8]      = kx0;
        *(bf16x8*)&Ks[krow][32 + kc8] = kx1;
        if (t < 128) *(bf16x8*)&Ks[lkrow][64 + lh8] = lkx;
        #pragma unroll
        for (int u = 0; u < 8; u++) VsT[vd80 + u][vr0] = vx0[u];
        #pragma unroll
        for (int u = 0; u < 8; u++) VsT[vd81 + u][vr1] = vx1[u];
        if (t < 128) {
            #pragma unroll
            for (int u = 0; u < 8; u++) LVsT[lvd8 + u][lvr] = lvx[u];
        }

        __syncthreads();   // B2: staging visible

        // ---- H tiles (this wave's 5 col-tiles), E from registers ----
        f32x4 hh[5];
        #pragma unroll
        for (int ct = 0; ct < 5; ct++) {
            hh[ct] = (f32x4)0.0f;
            hh[ct] = MFMA16(af[0], ef[ct][0], hh[ct]);
            hh[ct] = MFMA16(af[1], ef[ct][1], hh[ct]);
        }
        #pragma unroll
        for (int ct = 0; ct < 5; ct++)
            #pragma unroll
            for (int reg = 0; reg < 4; reg++)
                Hs[m0 + quad * 4 + reg][ct * 16 + ln] = (bf16)hh[ct][reg];

        // ---- scores = Q' @ K'^T (K' from LDS) ----
        f32x4 sc[4];
        #pragma unroll
        for (int nt = 0; nt < 4; nt++) {
            const bf16* kr = &Ks[nt * 16 + ln][quad * 8];
            sc[nt] = (f32x4)0.0f;
            sc[nt] = MFMA16(af[0], *(const bf16x8*)(kr),      sc[nt]);
            sc[nt] = MFMA16(af[1], *(const bf16x8*)(kr + 32), sc[nt]);
            sc[nt] = MFMA16(af[2], *(const bf16x8*)(kr + 64), sc[nt]);
        }

        // ---- softmax (same-wave Hs read) ----
        float sv[4][4];
        #pragma unroll
        for (int nt = 0; nt < 4; nt++) {
            int n = nt * 16 + ln;
            #pragma unroll
            for (int reg = 0; reg < 4; reg++) {
                int rr = quad * 4 + reg;
                sv[nt][reg] = sc[nt][reg] + (float)Hs[m0 + rr][rr - n + 63] + msv[nt];
            }
        }
        #pragma unroll
        for (int reg = 0; reg < 4; reg++) {
            float rmax = fmaxf(fmaxf(sv[0][reg], sv[1][reg]), fmaxf(sv[2][reg], sv[3][reg]));
            #pragma unroll
            for (int off = 1; off < 16; off <<= 1)
                rmax = fmaxf(rmax, __shfl_xor(rmax, off));
            float mnew  = fmaxf(mrow[reg], rmax);
            float alpha = __expf(mrow[reg] - mnew);
            float rsum = 0.0f;
            #pragma unroll
            for (int nt = 0; nt < 4; nt++) {
                float p = __expf(sv[nt][reg] - mnew);
                sv[nt][reg] = p;
                rsum += p;
            }
            #pragma unroll
            for (int off = 1; off < 16; off <<= 1)
                rsum += __shfl_xor(rsum, off);
            lrow[reg] = lrow[reg] * alpha + rsum;
            mrow[reg] = mnew;
            #pragma unroll
            for (int nt = 0; nt < 4; nt++) co[nt][reg] *= alpha;
            cl[reg] *= alpha;
        }
        #pragma unroll
        for (int nt = 0; nt < 4; nt++)
            #pragma unroll
            for (int reg = 0; reg < 4; reg++)
                Ps[m0 + quad * 4 + reg][nt * 16 + ln] = (bf16)sv[nt][reg];

        // ---- ctx += P @ V ; lctx += P @ LV (Ps same-wave) ----
        #pragma unroll
        for (int ks = 0; ks < 2; ks++) {
            bf16x8 ap = *(const bf16x8*)&Ps[m0 + ln][ks * 32 + quad * 8];
            cl = MFMA16(ap, *(const bf16x8*)&LVsT[ln][ks * 32 + quad * 8], cl);
            #pragma unroll
            for (int nt = 0; nt < 4; nt++)
                co[nt] = MFMA16(ap,
                                *(const bf16x8*)&VsT[nt * 16 + ln][ks * 32 + quad * 8],
                                co[nt]);
        }
    }

    // ---- epilogue ----
    #pragma unroll
    for (int reg = 0; reg < 4; reg++) {
        int s = l0 + m0 + quad * 4 + reg;
        float inv = 1.0f / lrow[reg];
        #pragma unroll
        for (int nt = 0; nt < 4; nt++)
            octx[(size_t)(b * S_LEN + s) * 1024 + h * 64 + nt * 16 + ln] = co[nt][reg] * inv;
        olctx[(size_t)(b * S_LEN + s) * 256 + h * 16 + ln] = cl[reg] * inv;
    }
}

// ---------------------------------------------------------------------------
extern "C" void kernel_launch(void* const* d_in, const int* in_sizes, int n_in,
                              void* d_out, int out_size, void* d_ws, size_t ws_size,
                              hipStream_t stream)
{
    (void)in_sizes; (void)n_in; (void)out_size; (void)ws_size;

    const float* hs   = (const float*)d_in[0];
    const float* lin  = (const float*)d_in[1];
    const float* mask = (const float*)d_in[2];
    const float* wq  = (const float*)d_in[3];  const float* bq  = (const float*)d_in[4];
    const float* wk  = (const float*)d_in[5];  const float* bk  = (const float*)d_in[6];
    const float* wv  = (const float*)d_in[7];  const float* bv  = (const float*)d_in[8];
    const float* lwq = (const float*)d_in[9];  const float* lbq = (const float*)d_in[10];
    const float* lwk = (const float*)d_in[11]; const float* lbk = (const float*)d_in[12];
    const float* lwv = (const float*)d_in[13]; const float* lbv = (const float*)d_in[14];
    const float* demb = (const float*)d_in[15];

    bf16* ws = (bf16*)d_ws;
    bf16* q    = ws;                  // 4,194,304
    bf16* k    = ws + 4194304;
    bf16* v    = ws + 8388608;
    bf16* lq   = ws + 12582912;       // 1,048,576
    bf16* lk   = ws + 13631488;
    bf16* lv   = ws + 14680064;
    bf16* de   = ws + 15728640;       // 262,080
    bf16* hsb  = ws + 16000000;       // 4,194,304
    bf16* linb = ws + 20194304;       // 1,048,576
    bf16* wqt  = ws + 21242880;       // 1,048,576
    bf16* wkt  = ws + 22291456;
    bf16* wvt  = ws + 23340032;
    bf16* lwqt = ws + 24388608;       // 65,536
    bf16* lwkt = ws + 24454144;
    bf16* lwvt = ws + 24519680;

    cvt4_kernel<<<dim3(4096), 256, 0, stream>>>(hs,  hsb,  1048576);
    cvt4_kernel<<<dim3(1024), 256, 0, stream>>>(lin, linb, 262144);
    cvt4_kernel<<<dim3(256),  256, 0, stream>>>(demb, de,  65520);
    cvtT_kernel<<<dim3(16, 16, 3), 256, 0, stream>>>(wq, wk, wv, wqt, wkt, wvt, 1024, 1024);
    cvtT_kernel<<<dim3(4, 4, 3),   256, 0, stream>>>(lwq, lwk, lwv, lwqt, lwkt, lwvt, 256, 256);

    projm_kernel<1024, 64><<<dim3(8, 32, 3), 256, 0, stream>>>(
        hsb, wqt, bq, wkt, bk, wvt, bv, q, k, v, 0.125f);
    projm_kernel<256, 16><<<dim3(2, 32, 3), 256, 0, stream>>>(
        linb, lwqt, lbq, lwkt, lbk, lwvt, lbv, lq, lk, lv, 0.25f);

    float* octx  = (float*)d_out;
    float* olctx = (float*)d_out + 4194304;
    attn_kernel<<<dim3(16, 64), 256, 0, stream>>>(
        q, k, v, lq, lk, lv, mask, de, octx, olctx);
}